// Round 7
// baseline (51.850 us; speedup 1.0000x reference)
//
#include <hip/hip_runtime.h>
#include <math.h>

#define OUT_H 7
#define OUT_W 7
#define NBINS 49
#define CCH   256
#define ELEMS (NBINS * CCH)    // 12544 outputs per box
#define KCH   7                // elements per thread: 7*256 = 1792, 7 blocks/box exact
// grid.x = 8 (multiple of 8): linear block id = x + 8*y -> XCD = x % 8,
// independent of box index y. Channel-slice x of EVERY box maps to the same
// XCD, so feature lines shared across overlapping boxes are fetched into one
// L2, not eight. (Round-4 win: FETCH 253 MB -> 90 MB.) Block x==7 exits.
#define GRIDX 8

typedef float f32x2 __attribute__((ext_vector_type(2)));
struct __attribute__((packed)) F2A { f32x2 v; } __attribute__((aligned(4)));

struct __align__(16) BoxHeader {
    unsigned long long planeBase;  // byte address of feat + b*C*H*W elements
    unsigned int       chanBytes;  // H*W*4
    unsigned int       pad;
};
struct __align__(16) BinParam {
    unsigned int o0;   // byte offset of row-A pair (covers vA0,vA1)
    unsigned int o1;   // byte offset of row-B pair (covers vB0,vB1)
    float w0, w1;      // weights for row-A pair
    float w2, w3;      // weights for row-B pair
    unsigned int pad0, pad1;
};

// ---------- pass 0: stable counting sort of boxes by (level, batch) ----------
// One block, 1024 threads. Clusters boxes that touch the same feature map
// (and batch slice) adjacently in dispatch order -> per-XCD L2 working set
// stays resident while that cluster is processed (temporal locality).
__global__ __launch_bounds__(1024)
void msroi_sort_kernel(const float* __restrict__ boxes, int M, int L,
                       int* __restrict__ perm)
{
    __shared__ unsigned s0[1024], s1[1024], s2[1024], s3[1024];
    __shared__ unsigned bases[8];
    int t = threadIdx.x;

    int bkt = -1;
    if (t < M) {
        float bx1 = boxes[t*4+0], by1 = boxes[t*4+1];
        float bx2 = boxes[t*4+2], by2 = boxes[t*4+3];
        float sz  = sqrtf((bx2 - bx1 + 1.0f) * (by2 - by1 + 1.0f));
        float lvf = floorf(4.0f + log2f(sz / 224.0f) + 1e-8f);
        lvf = fminf(fmaxf(lvf, 2.0f), 5.0f);
        int lv = (int)lvf - 2;          // 0..3
        int b  = t / L;                 // 0..1
        bkt = lv * 2 + b;               // 0..7
    }

    // 8 buckets packed as 16-bit halves of 4 scan arrays
    unsigned f0 = 0, f1 = 0, f2 = 0, f3 = 0;
    if (bkt >= 0) {
        unsigned inc = 1u << ((bkt & 1) * 16);
        switch (bkt >> 1) {
            case 0: f0 = inc; break;
            case 1: f1 = inc; break;
            case 2: f2 = inc; break;
            default: f3 = inc; break;
        }
    }
    s0[t] = f0; s1[t] = f1; s2[t] = f2; s3[t] = f3;
    __syncthreads();

    // Hillis-Steele inclusive scan over 1024 entries (10 steps)
    for (int off = 1; off < 1024; off <<= 1) {
        unsigned v0 = 0, v1 = 0, v2 = 0, v3 = 0;
        if (t >= off) { v0 = s0[t-off]; v1 = s1[t-off]; v2 = s2[t-off]; v3 = s3[t-off]; }
        __syncthreads();
        s0[t] += v0; s1[t] += v1; s2[t] += v2; s3[t] += v3;
        __syncthreads();
    }

    if (t == 0) {
        unsigned tot[8], run = 0;
        tot[0] = s0[1023] & 0xFFFFu; tot[1] = s0[1023] >> 16;
        tot[2] = s1[1023] & 0xFFFFu; tot[3] = s1[1023] >> 16;
        tot[4] = s2[1023] & 0xFFFFu; tot[5] = s2[1023] >> 16;
        tot[6] = s3[1023] & 0xFFFFu; tot[7] = s3[1023] >> 16;
        for (int k = 0; k < 8; ++k) { bases[k] = run; run += tot[k]; }
    }
    __syncthreads();

    if (bkt >= 0) {
        unsigned packed;
        switch (bkt >> 1) {
            case 0: packed = s0[t]; break;
            case 1: packed = s1[t]; break;
            case 2: packed = s2[t]; break;
            default: packed = s3[t]; break;
        }
        unsigned rank = ((packed >> ((bkt & 1) * 16)) & 0xFFFFu) - 1u;
        perm[bases[bkt] + rank] = t;
    }
}

__global__ void msroi_iota_kernel(int* __restrict__ perm, int M)
{
    int i = blockIdx.x * blockDim.x + threadIdx.x;
    if (i < M) perm[i] = i;
}

// ---------- pass 1: per-(box,bin) parameter precompute (tiny) ----------
__global__ void msroi_pre_kernel(const float* __restrict__ f0,
                                 const float* __restrict__ f1,
                                 const float* __restrict__ f2,
                                 const float* __restrict__ f3,
                                 const float* __restrict__ boxes,
                                 BoxHeader* __restrict__ hdrs,
                                 BinParam*  __restrict__ prm,
                                 int M, int L)
{
    int tid = blockIdx.x * blockDim.x + threadIdx.x;
    if (tid >= M * NBINS) return;
    int m   = tid / NBINS;
    int bin = tid - m * NBINS;
    int yh  = bin / OUT_W;
    int xw  = bin - yh * OUT_W;

    float bx1 = boxes[m*4+0], by1 = boxes[m*4+1];
    float bx2 = boxes[m*4+2], by2 = boxes[m*4+3];

    float sz  = sqrtf((bx2 - bx1 + 1.0f) * (by2 - by1 + 1.0f));
    float lvf = floorf(4.0f + log2f(sz / 224.0f) + 1e-8f);
    lvf = fminf(fmaxf(lvf, 2.0f), 5.0f);
    int lv = (int)lvf - 2;

    const float* feat; int H, W; float scale;
    switch (lv) {
        case 0:  feat = f0; H = 256; W = 256; scale = 0.25f;    break;
        case 1:  feat = f1; H = 128; W = 128; scale = 0.125f;   break;
        case 2:  feat = f2; H = 64;  W = 64;  scale = 0.0625f;  break;
        default: feat = f3; H = 32;  W = 32;  scale = 0.03125f; break;
    }

    if (bin == 0) {
        int b = m / L;
        BoxHeader h;
        h.planeBase = (unsigned long long)(const void*)(feat + (size_t)b * CCH * H * W);
        h.chanBytes = (unsigned int)(H * W * 4);
        h.pad = 0;
        hdrs[m] = h;
    }

    float x1 = bx1 * scale, y1 = by1 * scale;
    float x2 = bx2 * scale, y2 = by2 * scale;
    float roi_w = fmaxf(x2 - x1, 1.0f);
    float roi_h = fmaxf(y2 - y1, 1.0f);
    float bin_w = roi_w * (1.0f / OUT_W);
    float bin_h = roi_h * (1.0f / OUT_H);
    float sx = x1 + ((float)xw + 0.5f) * bin_w;
    float sy = y1 + ((float)yh + 0.5f) * bin_h;

    // _bilinear_axis(x): pair covers (xA, xA+1)
    bool  vx  = (sx >= -1.0f) && (sx <= (float)W);
    float scx = fmaxf(sx, 0.0f);
    int   xlr = (int)floorf(scx);
    bool  hxf = xlr >= (W - 1);
    float lx  = hxf ? 0.0f : (scx - (float)xlr);
    int   xA  = hxf ? (W - 2) : xlr;
    float wxA = hxf ? 0.0f : (1.0f - lx);
    float wxB = hxf ? 1.0f : lx;

    // _bilinear_axis(y): two row loads at rows rA, rB
    bool  vy  = (sy >= -1.0f) && (sy <= (float)H);
    float scy = fmaxf(sy, 0.0f);
    int   ylr = (int)floorf(scy);
    bool  hyf = ylr >= (H - 1);
    int   rA  = hyf ? (H - 1) : ylr;
    int   rB  = hyf ? (H - 1) : (ylr + 1);
    float ly  = hyf ? 0.0f : (scy - (float)ylr);
    float wyA = 1.0f - ly;
    float wyB = ly;

    float vmask = (vx && vy) ? 1.0f : 0.0f;

    BinParam p;
    p.o0 = (unsigned)((rA * W + xA) * 4);
    p.o1 = (unsigned)((rB * W + xA) * 4);
    p.w0 = vmask * wyA * wxA;
    p.w1 = vmask * wyA * wxB;
    p.w2 = vmask * wyB * wxA;
    p.w3 = vmask * wyB * wxB;
    p.pad0 = 0; p.pad1 = 0;
    prm[tid] = p;
}

// ---------- pass 2: gather + blend (hot) ----------
// Block handles exactly KCH*256 = 1792 consecutive elements of one box as
// KCH coalesced chunks (no tail guard). Params staged in LDS as SoA
// (stride-4 ds_read -> conflict-free). Loads issued in a separate phase
// into statically-indexed register arrays to force 14-deep MLP. Boxes are
// visited in perm[] (level,batch)-sorted order for L2 temporal locality;
// writes go to the original slot, so order is correctness-neutral.
__global__ __launch_bounds__(256, 2)
void msroi_gather_kernel(const BoxHeader* __restrict__ hdrs,
                         const BinParam*  __restrict__ prm,
                         const int*       __restrict__ perm,
                         float* __restrict__ out)
{
    __shared__ unsigned so0[NBINS], so1[NBINS];
    __shared__ float    sw0[NBINS], sw1[NBINS], sw2[NBINS], sw3[NBINS];

    int bx = blockIdx.x;
    if (bx >= 7) return;                   // padded block (x==7): uniform exit
    int m   = perm[blockIdx.y];            // box (uniform per block)
    int tid = threadIdx.x;

    if (tid < NBINS) {
        BinParam p = prm[(size_t)m * NBINS + tid];
        so0[tid] = p.o0; so1[tid] = p.o1;
        sw0[tid] = p.w0; sw1[tid] = p.w1;
        sw2[tid] = p.w2; sw3[tid] = p.w3;
    }
    __syncthreads();

    BoxHeader h = hdrs[m];
    const char* base = (const char*)h.planeBase;
    int e_base = bx * (256 * KCH) + tid;   // e = e_base + k*256 < 12544 always

    f32x2 r0[KCH], r1[KCH];
    float w0[KCH], w1[KCH], w2[KCH], w3[KCH];

    #pragma unroll
    for (int k = 0; k < KCH; ++k) {
        int e = e_base + k * 256;
        unsigned c   = (unsigned)e / NBINS;        // magic-mul div
        unsigned bin = (unsigned)e - c * NBINS;
        const char* plane = base + (unsigned long long)c
                                 * (unsigned long long)h.chanBytes;
        unsigned o0 = so0[bin], o1 = so1[bin];
        w0[k] = sw0[bin]; w1[k] = sw1[bin];
        w2[k] = sw2[bin]; w3[k] = sw3[bin];
        r0[k] = ((const F2A*)(plane + o0))->v;     // (vA0, vA1)
        r1[k] = ((const F2A*)(plane + o1))->v;     // (vB0, vB1)
    }

    size_t outBase = (size_t)m * ELEMS + (size_t)e_base;
    #pragma unroll
    for (int k = 0; k < KCH; ++k) {
        out[outBase + (size_t)k * 256] =
            r0[k].x * w0[k] + r0[k].y * w1[k] + r1[k].x * w2[k] + r1[k].y * w3[k];
    }
}

// ---------- fallback: monolithic kernel (used only if ws too small) ----------
__global__ void msroi_align_kernel(const float* __restrict__ f0,
                                   const float* __restrict__ f1,
                                   const float* __restrict__ f2,
                                   const float* __restrict__ f3,
                                   const float* __restrict__ boxes,
                                   float* __restrict__ out,
                                   int M, int C, int L, int total)
{
    int idx = blockIdx.x * blockDim.x + threadIdx.x;
    if (idx >= total) return;

    int xw = idx % OUT_W;
    int t  = idx / OUT_W;
    int yh = t % OUT_H;
    t /= OUT_H;
    int c = t % C;
    int m = t / C;
    int b = m / L;

    float bx1 = boxes[m*4+0], by1 = boxes[m*4+1];
    float bx2 = boxes[m*4+2], by2 = boxes[m*4+3];

    float sz  = sqrtf((bx2 - bx1 + 1.0f) * (by2 - by1 + 1.0f));
    float lvf = floorf(4.0f + log2f(sz / 224.0f) + 1e-8f);
    lvf = fminf(fmaxf(lvf, 2.0f), 5.0f);
    int lv = (int)lvf - 2;

    const float* feat; int H, W; float scale;
    switch (lv) {
        case 0:  feat = f0; H = 256; W = 256; scale = 0.25f;    break;
        case 1:  feat = f1; H = 128; W = 128; scale = 0.125f;   break;
        case 2:  feat = f2; H = 64;  W = 64;  scale = 0.0625f;  break;
        default: feat = f3; H = 32;  W = 32;  scale = 0.03125f; break;
    }

    float x1 = bx1 * scale, y1 = by1 * scale;
    float x2 = bx2 * scale, y2 = by2 * scale;
    float roi_w = fmaxf(x2 - x1, 1.0f);
    float roi_h = fmaxf(y2 - y1, 1.0f);
    float bin_w = roi_w * (1.0f / OUT_W);
    float bin_h = roi_h * (1.0f / OUT_H);
    float sx = x1 + ((float)xw + 0.5f) * bin_w;
    float sy = y1 + ((float)yh + 0.5f) * bin_h;

    bool  vx  = (sx >= -1.0f) && (sx <= (float)W);
    float scx = fmaxf(sx, 0.0f);
    int   xlr = (int)floorf(scx);
    bool  hxf = xlr >= (W - 1);
    int   xl  = hxf ? (W - 1) : xlr;
    int   xh  = hxf ? (W - 1) : (xlr + 1);
    float lx  = hxf ? 0.0f : (scx - (float)xlr);

    bool  vy  = (sy >= -1.0f) && (sy <= (float)H);
    float scy = fmaxf(sy, 0.0f);
    int   ylr = (int)floorf(scy);
    bool  hyf = ylr >= (H - 1);
    int   yl  = hyf ? (H - 1) : ylr;
    int   yhh = hyf ? (H - 1) : (ylr + 1);
    float ly  = hyf ? 0.0f : (scy - (float)ylr);

    float val = 0.0f;
    if (vx && vy) {
        size_t base = ((size_t)b * (size_t)C + (size_t)c) * (size_t)(H * W);
        const float* p = feat + base;
        float v00 = p[(size_t)yl  * W + xl];
        float v01 = p[(size_t)yl  * W + xh];
        float v10 = p[(size_t)yhh * W + xl];
        float v11 = p[(size_t)yhh * W + xh];
        float hy = 1.0f - ly, hx = 1.0f - lx;
        val = v00 * (hy * hx) + v01 * (hy * lx) + v10 * (ly * hx) + v11 * (ly * lx);
    }
    out[idx] = val;
}

extern "C" void kernel_launch(void* const* d_in, const int* in_sizes, int n_in,
                              void* d_out, int out_size, void* d_ws, size_t ws_size,
                              hipStream_t stream) {
    const float* f0    = (const float*)d_in[0];
    const float* f1    = (const float*)d_in[1];
    const float* f2    = (const float*)d_in[2];
    const float* f3    = (const float*)d_in[3];
    const float* boxes = (const float*)d_in[4];
    float* out = (float*)d_out;

    const int N = 2;
    const int M = in_sizes[4] / 4;   // total boxes (N*L)
    const int L = M / N;             // boxes per batch
    const int total = M * CCH * NBINS;

    size_t prmBytes  = (size_t)M * NBINS * sizeof(BinParam);
    size_t hdrBytes  = (size_t)M * sizeof(BoxHeader);
    size_t permBytes = (size_t)M * sizeof(int);
    size_t need = prmBytes + hdrBytes + permBytes;

    if (ws_size >= need) {
        BinParam*  prm  = (BinParam*)d_ws;
        BoxHeader* hdrs = (BoxHeader*)((char*)d_ws + prmBytes);
        int*       perm = (int*)((char*)d_ws + prmBytes + hdrBytes);

        if (M <= 1024) {
            msroi_sort_kernel<<<1, 1024, 0, stream>>>(boxes, M, L, perm);
        } else {
            msroi_iota_kernel<<<(M + 255) / 256, 256, 0, stream>>>(perm, M);
        }

        int preThreads = M * NBINS;
        msroi_pre_kernel<<<(preThreads + 255) / 256, 256, 0, stream>>>(
            f0, f1, f2, f3, boxes, hdrs, prm, M, L);

        dim3 grid(GRIDX, M);  // 7 active blocks/box (block 7 exits); XCD = x % 8
        msroi_gather_kernel<<<grid, 256, 0, stream>>>(hdrs, prm, perm, out);
    } else {
        int block = 256;
        int grid = (total + block - 1) / block;
        msroi_align_kernel<<<grid, block, 0, stream>>>(f0, f1, f2, f3, boxes, out,
                                                       M, CCH, L, total);
    }
}

// Round 8
// 43.204 us; speedup vs baseline: 1.2001x; 1.2001x over previous
//
#include <hip/hip_runtime.h>
#include <math.h>

#define OUT_H 7
#define OUT_W 7
#define NBINS 49
#define CCH   256
#define ELEMS (NBINS * CCH)    // 12544 outputs per box
#define KCH   7                // elements per thread: 7*256 = 1792, 7 blocks/box exact
// grid.x = 8 (multiple of 8): linear block id = x + 8*y -> XCD = x % 8,
// independent of box index y. Channel-slice x of EVERY box maps to the same
// XCD, so feature lines shared across overlapping boxes are fetched into one
// L2, not eight. (Round-4 win: FETCH 253 MB -> 90 MB.) Block x==7 exits.
#define GRIDX 8

typedef float f32x2 __attribute__((ext_vector_type(2)));
struct __attribute__((packed)) F2A { f32x2 v; } __attribute__((aligned(4)));

// ---------- fused kernel: per-block param compute + gather + blend ----------
// One block = 1792 consecutive output elements of one box (7 blocks/box).
// All threads compute the (block-uniform) level/plane geometry; threads
// 0..48 compute the 49 bilinear bin params into SoA LDS (conflict-free
// stride-4 reads); then the R6-proven gather body: KCH statically-indexed
// register chunks -> 14 loads in flight per thread (latency -> throughput).
__global__ __launch_bounds__(256, 2)
void msroi_fused_kernel(const float* __restrict__ f0,
                        const float* __restrict__ f1,
                        const float* __restrict__ f2,
                        const float* __restrict__ f3,
                        const float* __restrict__ boxes,
                        float* __restrict__ out,
                        int L)
{
    __shared__ unsigned so0[NBINS], so1[NBINS];
    __shared__ float    sw0[NBINS], sw1[NBINS], sw2[NBINS], sw3[NBINS];

    int bx = blockIdx.x;
    if (bx >= 7) return;                   // padded block (x==7): uniform exit
    int m   = blockIdx.y;                  // box (uniform per block)
    int tid = threadIdx.x;

    // --- block-uniform: box -> level -> plane geometry (every thread) ---
    float bx1 = boxes[m*4+0], by1 = boxes[m*4+1];
    float bx2 = boxes[m*4+2], by2 = boxes[m*4+3];

    float sz  = sqrtf((bx2 - bx1 + 1.0f) * (by2 - by1 + 1.0f));
    float lvf = floorf(4.0f + log2f(sz / 224.0f) + 1e-8f);
    lvf = fminf(fmaxf(lvf, 2.0f), 5.0f);
    int lv = (int)lvf - 2;

    const float* feat; int H, W; float scale;
    switch (lv) {
        case 0:  feat = f0; H = 256; W = 256; scale = 0.25f;    break;
        case 1:  feat = f1; H = 128; W = 128; scale = 0.125f;   break;
        case 2:  feat = f2; H = 64;  W = 64;  scale = 0.0625f;  break;
        default: feat = f3; H = 32;  W = 32;  scale = 0.03125f; break;
    }
    int b = m / L;
    const char* base = (const char*)(feat + (size_t)b * CCH * (size_t)(H * W));
    unsigned chanBytes = (unsigned)(H * W * 4);

    // --- threads 0..48: per-bin bilinear params into SoA LDS ---
    if (tid < NBINS) {
        int yh = tid / OUT_W;
        int xw = tid - yh * OUT_W;

        float x1 = bx1 * scale, y1 = by1 * scale;
        float x2 = bx2 * scale, y2 = by2 * scale;
        float roi_w = fmaxf(x2 - x1, 1.0f);
        float roi_h = fmaxf(y2 - y1, 1.0f);
        float bin_w = roi_w * (1.0f / OUT_W);
        float bin_h = roi_h * (1.0f / OUT_H);
        float sx = x1 + ((float)xw + 0.5f) * bin_w;
        float sy = y1 + ((float)yh + 0.5f) * bin_h;

        // _bilinear_axis(x): pair covers (xA, xA+1)
        bool  vx  = (sx >= -1.0f) && (sx <= (float)W);
        float scx = fmaxf(sx, 0.0f);
        int   xlr = (int)floorf(scx);
        bool  hxf = xlr >= (W - 1);
        float lx  = hxf ? 0.0f : (scx - (float)xlr);
        int   xA  = hxf ? (W - 2) : xlr;
        float wxA = hxf ? 0.0f : (1.0f - lx);
        float wxB = hxf ? 1.0f : lx;

        // _bilinear_axis(y): two row loads at rows rA, rB
        bool  vy  = (sy >= -1.0f) && (sy <= (float)H);
        float scy = fmaxf(sy, 0.0f);
        int   ylr = (int)floorf(scy);
        bool  hyf = ylr >= (H - 1);
        int   rA  = hyf ? (H - 1) : ylr;
        int   rB  = hyf ? (H - 1) : (ylr + 1);
        float ly  = hyf ? 0.0f : (scy - (float)ylr);
        float wyA = 1.0f - ly;
        float wyB = ly;

        float vmask = (vx && vy) ? 1.0f : 0.0f;

        so0[tid] = (unsigned)((rA * W + xA) * 4);
        so1[tid] = (unsigned)((rB * W + xA) * 4);
        sw0[tid] = vmask * wyA * wxA;
        sw1[tid] = vmask * wyA * wxB;
        sw2[tid] = vmask * wyB * wxA;
        sw3[tid] = vmask * wyB * wxB;
    }
    __syncthreads();

    // --- gather + blend (R6-proven body) ---
    int e_base = bx * (256 * KCH) + tid;   // e = e_base + k*256 < 12544 always

    f32x2 r0[KCH], r1[KCH];
    float w0[KCH], w1[KCH], w2[KCH], w3[KCH];

    #pragma unroll
    for (int k = 0; k < KCH; ++k) {
        int e = e_base + k * 256;
        unsigned c   = (unsigned)e / NBINS;        // magic-mul div
        unsigned bin = (unsigned)e - c * NBINS;
        const char* plane = base + (unsigned long long)c
                                 * (unsigned long long)chanBytes;
        unsigned o0 = so0[bin], o1 = so1[bin];
        w0[k] = sw0[bin]; w1[k] = sw1[bin];
        w2[k] = sw2[bin]; w3[k] = sw3[bin];
        r0[k] = ((const F2A*)(plane + o0))->v;     // (vA0, vA1)
        r1[k] = ((const F2A*)(plane + o1))->v;     // (vB0, vB1)
    }

    size_t outBase = (size_t)m * ELEMS + (size_t)e_base;
    #pragma unroll
    for (int k = 0; k < KCH; ++k) {
        out[outBase + (size_t)k * 256] =
            r0[k].x * w0[k] + r0[k].y * w1[k] + r1[k].x * w2[k] + r1[k].y * w3[k];
    }
}

extern "C" void kernel_launch(void* const* d_in, const int* in_sizes, int n_in,
                              void* d_out, int out_size, void* d_ws, size_t ws_size,
                              hipStream_t stream) {
    const float* f0    = (const float*)d_in[0];
    const float* f1    = (const float*)d_in[1];
    const float* f2    = (const float*)d_in[2];
    const float* f3    = (const float*)d_in[3];
    const float* boxes = (const float*)d_in[4];
    float* out = (float*)d_out;

    const int N = 2;
    const int M = in_sizes[4] / 4;   // total boxes (N*L)
    const int L = M / N;             // boxes per batch

    dim3 grid(GRIDX, M);  // 7 active blocks/box (block 7 exits); XCD = x % 8
    msroi_fused_kernel<<<grid, 256, 0, stream>>>(f0, f1, f2, f3, boxes, out, L);
}

// Round 9
// 40.894 us; speedup vs baseline: 1.2679x; 1.0565x over previous
//
#include <hip/hip_runtime.h>
#include <math.h>

#define OUT_H 7
#define OUT_W 7
#define NBINS 49
#define CCH   256
#define ELEMS (NBINS * CCH)    // 12544 outputs per box
#define KCH   7                // elements per thread: 7*256 = 1792, 7 blocks/box exact
// grid.x = 8 (multiple of 8): linear block id = x + 8*y -> XCD = x % 8,
// independent of box index y. Channel-slice x of EVERY box maps to the same
// XCD, so feature lines shared across overlapping boxes are fetched into one
// L2, not eight. (Round-4 win: FETCH 253 MB -> 90 MB.) Block x==7 exits.
#define GRIDX 8

typedef float f32x2 __attribute__((ext_vector_type(2)));
struct __attribute__((packed)) F2A { f32x2 v; } __attribute__((aligned(4)));

// ---------- fused kernel: per-block param compute + gather + blend ----------
// One block = 1792 consecutive output elements of one box (7 blocks/box).
// All threads compute the (block-uniform) level/plane geometry; threads
// 0..48 compute the 49 bilinear bin params into SoA LDS (conflict-free
// stride-4 reads); then the R6-proven gather body: KCH statically-indexed
// register chunks -> 14 loads in flight per thread (latency -> throughput).
// launch_bounds(256,4): allow 4 blocks/CU (vs 2) -> 2x resident waves ->
// 2x outstanding scattered loads per CU. Output stores are non-temporal
// (bypass L2) so the 50 MB write stream doesn't evict feature lines.
__global__ __launch_bounds__(256, 4)
void msroi_fused_kernel(const float* __restrict__ f0,
                        const float* __restrict__ f1,
                        const float* __restrict__ f2,
                        const float* __restrict__ f3,
                        const float* __restrict__ boxes,
                        float* __restrict__ out,
                        int L)
{
    __shared__ unsigned so0[NBINS], so1[NBINS];
    __shared__ float    sw0[NBINS], sw1[NBINS], sw2[NBINS], sw3[NBINS];

    int bx = blockIdx.x;
    if (bx >= 7) return;                   // padded block (x==7): uniform exit
    int m   = blockIdx.y;                  // box (uniform per block)
    int tid = threadIdx.x;

    // --- block-uniform: box -> level -> plane geometry (every thread) ---
    float bx1 = boxes[m*4+0], by1 = boxes[m*4+1];
    float bx2 = boxes[m*4+2], by2 = boxes[m*4+3];

    float sz  = sqrtf((bx2 - bx1 + 1.0f) * (by2 - by1 + 1.0f));
    float lvf = floorf(4.0f + log2f(sz / 224.0f) + 1e-8f);
    lvf = fminf(fmaxf(lvf, 2.0f), 5.0f);
    int lv = (int)lvf - 2;

    const float* feat; int H, W; float scale;
    switch (lv) {
        case 0:  feat = f0; H = 256; W = 256; scale = 0.25f;    break;
        case 1:  feat = f1; H = 128; W = 128; scale = 0.125f;   break;
        case 2:  feat = f2; H = 64;  W = 64;  scale = 0.0625f;  break;
        default: feat = f3; H = 32;  W = 32;  scale = 0.03125f; break;
    }
    int b = m / L;
    const char* base = (const char*)(feat + (size_t)b * CCH * (size_t)(H * W));
    unsigned chanBytes = (unsigned)(H * W * 4);

    // --- threads 0..48: per-bin bilinear params into SoA LDS ---
    if (tid < NBINS) {
        int yh = tid / OUT_W;
        int xw = tid - yh * OUT_W;

        float x1 = bx1 * scale, y1 = by1 * scale;
        float x2 = bx2 * scale, y2 = by2 * scale;
        float roi_w = fmaxf(x2 - x1, 1.0f);
        float roi_h = fmaxf(y2 - y1, 1.0f);
        float bin_w = roi_w * (1.0f / OUT_W);
        float bin_h = roi_h * (1.0f / OUT_H);
        float sx = x1 + ((float)xw + 0.5f) * bin_w;
        float sy = y1 + ((float)yh + 0.5f) * bin_h;

        // _bilinear_axis(x): pair covers (xA, xA+1)
        bool  vx  = (sx >= -1.0f) && (sx <= (float)W);
        float scx = fmaxf(sx, 0.0f);
        int   xlr = (int)floorf(scx);
        bool  hxf = xlr >= (W - 1);
        float lx  = hxf ? 0.0f : (scx - (float)xlr);
        int   xA  = hxf ? (W - 2) : xlr;
        float wxA = hxf ? 0.0f : (1.0f - lx);
        float wxB = hxf ? 1.0f : lx;

        // _bilinear_axis(y): two row loads at rows rA, rB
        bool  vy  = (sy >= -1.0f) && (sy <= (float)H);
        float scy = fmaxf(sy, 0.0f);
        int   ylr = (int)floorf(scy);
        bool  hyf = ylr >= (H - 1);
        int   rA  = hyf ? (H - 1) : ylr;
        int   rB  = hyf ? (H - 1) : (ylr + 1);
        float ly  = hyf ? 0.0f : (scy - (float)ylr);
        float wyA = 1.0f - ly;
        float wyB = ly;

        float vmask = (vx && vy) ? 1.0f : 0.0f;

        so0[tid] = (unsigned)((rA * W + xA) * 4);
        so1[tid] = (unsigned)((rB * W + xA) * 4);
        sw0[tid] = vmask * wyA * wxA;
        sw1[tid] = vmask * wyA * wxB;
        sw2[tid] = vmask * wyB * wxA;
        sw3[tid] = vmask * wyB * wxB;
    }
    __syncthreads();

    // --- gather + blend (R6-proven body) ---
    int e_base = bx * (256 * KCH) + tid;   // e = e_base + k*256 < 12544 always

    f32x2 r0[KCH], r1[KCH];
    float w0[KCH], w1[KCH], w2[KCH], w3[KCH];

    #pragma unroll
    for (int k = 0; k < KCH; ++k) {
        int e = e_base + k * 256;
        unsigned c   = (unsigned)e / NBINS;        // magic-mul div
        unsigned bin = (unsigned)e - c * NBINS;
        const char* plane = base + (unsigned long long)c
                                 * (unsigned long long)chanBytes;
        unsigned o0 = so0[bin], o1 = so1[bin];
        w0[k] = sw0[bin]; w1[k] = sw1[bin];
        w2[k] = sw2[bin]; w3[k] = sw3[bin];
        r0[k] = ((const F2A*)(plane + o0))->v;     // (vA0, vA1)
        r1[k] = ((const F2A*)(plane + o1))->v;     // (vB0, vB1)
    }

    size_t outBase = (size_t)m * ELEMS + (size_t)e_base;
    #pragma unroll
    for (int k = 0; k < KCH; ++k) {
        float v = r0[k].x * w0[k] + r0[k].y * w1[k]
                + r1[k].x * w2[k] + r1[k].y * w3[k];
        __builtin_nontemporal_store(v, &out[outBase + (size_t)k * 256]);
    }
}

extern "C" void kernel_launch(void* const* d_in, const int* in_sizes, int n_in,
                              void* d_out, int out_size, void* d_ws, size_t ws_size,
                              hipStream_t stream) {
    const float* f0    = (const float*)d_in[0];
    const float* f1    = (const float*)d_in[1];
    const float* f2    = (const float*)d_in[2];
    const float* f3    = (const float*)d_in[3];
    const float* boxes = (const float*)d_in[4];
    float* out = (float*)d_out;

    const int N = 2;
    const int M = in_sizes[4] / 4;   // total boxes (N*L)
    const int L = M / N;             // boxes per batch

    dim3 grid(GRIDX, M);  // 7 active blocks/box (block 7 exits); XCD = x % 8
    msroi_fused_kernel<<<grid, 256, 0, stream>>>(f0, f1, f2, f3, boxes, out, L);
}